// Round 15
// baseline (191.328 us; speedup 1.0000x reference)
//
#include <hip/hip_runtime.h>
#include <math.h>

#define NATOMS  512
#define MROWS   64
#define BATCH   65536
#define BT      4           // batch columns per block (8 waves, 2 waves/col)
#define NSPARSE 5
#define DEPSF   1e-6f

// ---------------------------------------------------------------------------
// prep: gram = D^T D (f64 accumulate -> f32). 1024 blocks x 256 threads.
// ---------------------------------------------------------------------------
__global__ void ksvd_prep(const float* __restrict__ D,
                          float* __restrict__ gram) {
  const int idx = blockIdx.x * 256 + threadIdx.x;     // 0 .. 512*512-1
  const int i = idx >> 9;
  const int j = idx & (NATOMS - 1);
  double acc = 0.0;
#pragma unroll 8
  for (int m = 0; m < MROWS; ++m)
    acc += (double)D[m * NATOMS + i] * (double)D[m * NATOMS + j];
  gram[idx] = (float)acc;
}

// ---------------------------------------------------------------------------
// wave64 max-reduce on the VALU via DPP (no LDS ops, no lgkmcnt waits).
// ---------------------------------------------------------------------------
__device__ __forceinline__ float wave_max_nonneg(float x) {
  int v = __builtin_bit_cast(int, x);
#define DPP_MAX_STEP(ctrl)                                                   \
  {                                                                          \
    const int t = __builtin_amdgcn_update_dpp(0, v, (ctrl), 0xf, 0xf, true); \
    v = __builtin_bit_cast(                                                  \
        int, fmaxf(__builtin_bit_cast(float, v), __builtin_bit_cast(float, t))); \
  }
  DPP_MAX_STEP(0x111)   // row_shr:1
  DPP_MAX_STEP(0x112)   // row_shr:2
  DPP_MAX_STEP(0x114)   // row_shr:4
  DPP_MAX_STEP(0x118)   // row_shr:8
  DPP_MAX_STEP(0x142)   // row_bcast15
  DPP_MAX_STEP(0x143)   // row_bcast31
#undef DPP_MAX_STEP
  return __builtin_bit_cast(float, __builtin_amdgcn_readlane(v, 63));
}

__device__ __forceinline__ float readlane_f(float v, int l) {
  return __builtin_bit_cast(float,
      __builtin_amdgcn_readlane(__builtin_bit_cast(int, v), l));
}

// ---------------------------------------------------------------------------
// main: block = 8 waves = 4 columns, TWO waves per column (half h = w&1 owns
// atoms 256h..256h+255, 4 per lane). Halving per-lane array state
// (dtxr 8->4, gc 32->16) targets VGPR ~32-40 -> ~24-29 waves/CU (occupancy
// was inverse-VGPR across R1-R14). The wave-uniform Cholesky/solve is
// duplicated in both waves (identical inputs -> identical results). Cross-
// wave argmax resolves via per-round LDS exchange + 1 barrier (distinct
// slots per round -> no extra barrier). Phase 1: wave w computes atoms
// 64w..64w+63 (1/lane) for all 4 columns with the same even/odd-m split
// accumulators -> dtx bit-identical to R9/R14 -> absmax must stay 0.015625.
// ---------------------------------------------------------------------------
__global__ __launch_bounds__(512, 2) void ksvd_main(
    const float* __restrict__ X, const float* __restrict__ D,
    const float* __restrict__ gram, float* __restrict__ out) {
  __shared__ union {
    float4 xs4[MROWS];               // 1 KB: 4 columns' x per m
    float  dtxT[BT][NATOMS];         // 8 KB: dtx transposed per column
  } sh;
  __shared__ float exv[BT][NSPARSE][2];   // per-round exchange: wave max
  __shared__ int   exn[BT][NSPARSE][2];   //                     wave argmax
  __shared__ float exd[BT][NSPARSE][2];   //                     winner's dtx

  const int t    = threadIdx.x;
  const int lane = t & 63;
  const int w    = t >> 6;                      // 0..7
  const int cw   = w >> 1;                      // column 0..3
  const int h    = w & 1;                       // half 0/1
  const int b0   = blockIdx.x * BT;

  // ---- stage X tile: one float4 (4 consecutive columns) per m
  if (t < MROWS)
    sh.xs4[t] = *reinterpret_cast<const float4*>(&X[(size_t)t * BATCH + b0]);
  __syncthreads();

  // ---- phase 1: wave w owns atoms 64w+lane (1/lane), all 4 columns.
  //      even/odd-m split accumulators: per-(atom,col) sum order == R9.
  const int aw = 64 * w + lane;
  float accA[BT], accB[BT];
#pragma unroll
  for (int c = 0; c < BT; ++c) { accA[c] = 0.f; accB[c] = 0.f; }

#pragma unroll 4
  for (int m = 0; m < MROWS; m += 2) {
    const float dA = D[m * NATOMS + aw];
    const float dB = D[(m + 1) * NATOMS + aw];
    const float4 xa = sh.xs4[m];
    const float4 xb = sh.xs4[m + 1];
    accA[0] = fmaf(dA, xa.x, accA[0]); accB[0] = fmaf(dB, xb.x, accB[0]);
    accA[1] = fmaf(dA, xa.y, accA[1]); accB[1] = fmaf(dB, xb.y, accB[1]);
    accA[2] = fmaf(dA, xa.z, accA[2]); accB[2] = fmaf(dB, xb.z, accB[2]);
    accA[3] = fmaf(dA, xa.w, accA[3]); accB[3] = fmaf(dB, xb.w, accB[3]);
  }
  __syncthreads();   // xs4 reads done before dtxT overwrites the union
#pragma unroll
  for (int c = 0; c < BT; ++c)
    sh.dtxT[c][aw] = accA[c] + accB[c];
  __syncthreads();

  // ---- phase 2: wave (cw,h) owns atoms 256h + 4*lane .. +3 of column cw
  const int cglob = b0 + cw;
  float dtxr[4];
  {
    const float4 f =
        *reinterpret_cast<const float4*>(&sh.dtxT[cw][256 * h + 4 * lane]);
    dtxr[0] = f.x; dtxr[1] = f.y; dtxr[2] = f.z; dtxr[3] = f.w;
  }

  int   idxs[NSPARSE];
  float gc[NSPARSE - 1][4];                 // this half's gram-column slice
  float L[NSPARSE][NSPARSE];                // wave-uniform Cholesky
  float inv_d[NSPARSE];
  float y[NSPARSE];
  float sol[NSPARSE];

#pragma unroll
  for (int k = 0; k < NSPARSE; ++k) {
    // local masked-free abs-argmax over this half's 4 slots
    float bv   = -1.0f;
    int   bn   = 0;
    float bdtx = 0.0f;
#pragma unroll
    for (int jj = 0; jj < 4; ++jj) {
      float cv = dtxr[jj];
#pragma unroll
      for (int s = 0; s < k; ++s) cv -= sol[s] * gc[s][jj];
      const float av = fabsf(cv);
      if (av > bv) { bv = av; bn = 256 * h + 4 * lane + jj; bdtx = dtxr[jj]; }
    }
    // wave-level resolve (DPP max + ballot lowest lane = first-max)
    const float wmax = wave_max_nonneg(bv);
    const unsigned long long own = __ballot(bv == wmax);
    const int owner = __ffsll((long long)own) - 1;
    int   widx = __builtin_amdgcn_readlane(bn, owner);
    float wdtx = readlane_f(bdtx, owner);
    widx = __builtin_amdgcn_readfirstlane(widx);

    // cross-wave exchange (distinct slots per round -> 1 barrier)
    if (lane == 0) {
      exv[cw][k][h] = wmax; exn[cw][k][h] = widx; exd[cw][k][h] = wdtx;
    }
    __syncthreads();
    const float v0 = exv[cw][k][0], v1 = exv[cw][k][1];
    const bool take0 = (v0 >= v1);            // equal -> half 0 = lower atom
    int idx = take0 ? exn[cw][k][0] : exn[cw][k][1];
    const float rhsk = take0 ? exd[cw][k][0] : exd[cw][k][1];
    idx = __builtin_amdgcn_readfirstlane(idx);
    idxs[k] = idx;

    // gram-column slice for future corr updates (consumed next round)
    if (k < NSPARSE - 1) {
      const float4 g = *reinterpret_cast<const float4*>(
          &gram[(size_t)idx * NATOMS + 256 * h + 4 * lane]);
      gc[k][0] = g.x; gc[k][1] = g.y; gc[k][2] = g.z; gc[k][3] = g.w;
    }

    // Gram row k entries: uniform (scalar) loads, as in R9/R14
    float arowf[NSPARSE];
#pragma unroll
    for (int j = 0; j < k; ++j)
      arowf[j] = gram[(size_t)idx * NATOMS + idxs[j]];
    const float gdiag = gram[(size_t)idx * NATOMS + idx];

    // incremental Cholesky row k of (G_active + eps*I), rsqrtf-based
    float ss = gdiag + DEPSF;
#pragma unroll
    for (int j = 0; j < k; ++j) {
      float ww = arowf[j];
#pragma unroll
      for (int tt = 0; tt < j; ++tt) ww -= L[k][tt] * L[j][tt];
      ww *= inv_d[j];
      L[k][j] = ww;
      ss -= ww * ww;
    }
    const float inv = rsqrtf(ss);
    L[k][k]  = ss * inv;
    inv_d[k] = inv;

    // forward substitution: only y[k] is new
    {
      float s2 = rhsk;
#pragma unroll
      for (int j = 0; j < k; ++j) s2 -= L[k][j] * y[j];
      y[k] = s2 * inv;
    }
    // backward substitution (full)
#pragma unroll
    for (int i = k; i >= 0; --i) {
      float s2 = y[i];
#pragma unroll
      for (int j = i + 1; j <= k; ++j) s2 -= L[j][i] * sol[j];
      sol[i] = s2 * inv_d[i];
    }
  }

  // ---- epilogue: half 0 scatters (both halves hold identical sol)
  if (h == 0 && lane == 0) {
#pragma unroll
    for (int s = 0; s < NSPARSE; ++s)
      out[(size_t)idxs[s] * BATCH + cglob] = sol[s];
  }
}

// ---------------------------------------------------------------------------
extern "C" void kernel_launch(void* const* d_in, const int* in_sizes, int n_in,
                              void* d_out, int out_size, void* d_ws,
                              size_t ws_size, hipStream_t stream) {
  (void)in_sizes; (void)n_in; (void)out_size; (void)ws_size;
  const float* X = (const float*)d_in[0];   // (64, 65536)
  const float* D = (const float*)d_in[1];   // (64, 512)
  float* out = (float*)d_out;               // (512, 65536)
  float* gram = (float*)d_ws;               // 1 MB scratch

  ksvd_prep<<<(NATOMS * NATOMS) / 256, 256, 0, stream>>>(D, gram);
  hipMemsetAsync(out, 0, (size_t)NATOMS * BATCH * sizeof(float), stream);
  ksvd_main<<<BATCH / BT, 512, 0, stream>>>(X, D, gram, out);
}